// Round 1
// baseline (1920.223 us; speedup 1.0000x reference)
//
#include <hip/hip_runtime.h>

typedef float f4 __attribute__((ext_vector_type(4)));
typedef short s8v __attribute__((ext_vector_type(8)));
typedef unsigned short us4 __attribute__((ext_vector_type(4)));

#define NEGV -1.0e10f

__device__ __forceinline__ unsigned short f2b(float f) {
    unsigned int u = __builtin_bit_cast(unsigned int, f);
    unsigned int r = u + 0x7fffu + ((u >> 16) & 1u);
    return (unsigned short)(r >> 16);
}

// ---------------- mask packing: int32 [B,1,S,S] -> 1 bit per element ----------------
__global__ __launch_bounds__(256) void pack_mask_kernel(const int* __restrict__ mask,
                                                        unsigned int* __restrict__ bits) {
    int w = blockIdx.x * blockDim.x + threadIdx.x;  // word over 16.8M bits / 32
    const int* p = mask + (size_t)w * 32;
    unsigned int r = 0;
#pragma unroll
    for (int i = 0; i < 32; i++) r |= (p[i] != 0) ? (1u << i) : 0u;
    bits[w] = r;
}

// ---------------- weight fp32 -> bf16 ----------------
__global__ __launch_bounds__(256) void cvt_w_kernel(
    const float* __restrict__ w0, const float* __restrict__ w1,
    const float* __restrict__ w2, const float* __restrict__ w3,
    unsigned short* __restrict__ o0, unsigned short* __restrict__ o1,
    unsigned short* __restrict__ o2, unsigned short* __restrict__ o3) {
    const float* src;
    unsigned short* dst;
    switch (blockIdx.y) {
        case 0: src = w0; dst = o0; break;
        case 1: src = w1; dst = o1; break;
        case 2: src = w2; dst = o2; break;
        default: src = w3; dst = o3; break;
    }
    int i = (blockIdx.x * blockDim.x + threadIdx.x) * 4;
    f4 v = *(const f4*)(src + i);
    us4 t;
    t.x = f2b(v.x); t.y = f2b(v.y); t.z = f2b(v.z); t.w = f2b(v.w);
    *(us4*)&dst[i] = t;
}

// ---------------- GEMM: C[M,N] = A[M,K] @ W[N,K]^T + bias, M=8192,N=K=1024 ----------------
// OUTM==0: out bf16 to [B,NH,S,HD] layout with scale; OUTM==1: out fp32 flat [M,N]
template <bool ABF16, int OUTM>
__global__ __launch_bounds__(256) void gemm_kernel(const void* __restrict__ Ap,
                                                   const unsigned short* __restrict__ Bw,
                                                   const float* __restrict__ bias,
                                                   void* __restrict__ Outp, float scale) {
    constexpr int K = 1024;
    __shared__ unsigned short As[128 * 32];
    __shared__ unsigned short Bs[128 * 32];
    const int tid = threadIdx.x;
    const int lane = tid & 63;
    const int wv = tid >> 6;
    const int wrow = (wv >> 1) * 64, wcol = (wv & 1) * 64;
    const int fr = lane & 15, fq = lane >> 4;
    const int bm = blockIdx.x * 128, bn = blockIdx.y * 128;
    const int srow = tid >> 1, scol = (tid & 1) * 16;

    f4 zero = {0.f, 0.f, 0.f, 0.f};
    f4 acc[4][4];
#pragma unroll
    for (int a = 0; a < 4; a++)
#pragma unroll
        for (int b2 = 0; b2 < 4; b2++) acc[a][b2] = zero;

    for (int k0 = 0; k0 < K; k0 += 32) {
        if (ABF16) {
            const unsigned short* A = (const unsigned short*)Ap + (size_t)(bm + srow) * K + k0 + scol;
            *(s8v*)&As[srow * 32 + scol] = *(const s8v*)A;
            *(s8v*)&As[srow * 32 + scol + 8] = *(const s8v*)(A + 8);
        } else {
            const float* A = (const float*)Ap + (size_t)(bm + srow) * K + k0 + scol;
            unsigned short t[16];
#pragma unroll
            for (int i = 0; i < 4; i++) {
                f4 v = *(const f4*)(A + i * 4);
                t[i * 4 + 0] = f2b(v.x); t[i * 4 + 1] = f2b(v.y);
                t[i * 4 + 2] = f2b(v.z); t[i * 4 + 3] = f2b(v.w);
            }
            *(s8v*)&As[srow * 32 + scol] = *(const s8v*)&t[0];
            *(s8v*)&As[srow * 32 + scol + 8] = *(const s8v*)&t[8];
        }
        {
            const unsigned short* Bp2 = Bw + (size_t)(bn + srow) * K + k0 + scol;
            *(s8v*)&Bs[srow * 32 + scol] = *(const s8v*)Bp2;
            *(s8v*)&Bs[srow * 32 + scol + 8] = *(const s8v*)(Bp2 + 8);
        }
        __syncthreads();
        s8v af[4], bf[4];
#pragma unroll
        for (int rt = 0; rt < 4; rt++) af[rt] = *(const s8v*)&As[(wrow + rt * 16 + fr) * 32 + fq * 8];
#pragma unroll
        for (int ct = 0; ct < 4; ct++) bf[ct] = *(const s8v*)&Bs[(wcol + ct * 16 + fr) * 32 + fq * 8];
#pragma unroll
        for (int rt = 0; rt < 4; rt++)
#pragma unroll
            for (int ct = 0; ct < 4; ct++)
                acc[rt][ct] = __builtin_amdgcn_mfma_f32_16x16x32_bf16(af[rt], bf[ct], acc[rt][ct], 0, 0, 0);
        __syncthreads();
    }
#pragma unroll
    for (int rt = 0; rt < 4; rt++) {
#pragma unroll
        for (int ct = 0; ct < 4; ct++) {
            int j = bn + wcol + ct * 16 + fr;
            float bj = bias[j];
#pragma unroll
            for (int r = 0; r < 4; r++) {
                int i = bm + wrow + rt * 16 + fq * 4 + r;
                float v = (acc[rt][ct][r] + bj) * scale;
                if (OUTM == 0) {
                    int batch = i >> 11, s = i & 2047, hh = j >> 6, d = j & 63;
                    ((unsigned short*)Outp)[(((size_t)(batch * 16 + hh) * 2048 + s) * 64) + d] = f2b(v);
                } else {
                    ((float*)Outp)[(size_t)i * 1024 + j] = v;
                }
            }
        }
    }
}

// ---------------- fused two-pass attention, per (qtile64, head, batch) ----------------
__global__ __launch_bounds__(256) void attn_kernel(const unsigned short* __restrict__ qh,
                                                   const unsigned short* __restrict__ kh,
                                                   const unsigned short* __restrict__ vh,
                                                   const unsigned int* __restrict__ mbits,
                                                   float* __restrict__ attn,
                                                   unsigned short* __restrict__ xh) {
    const int S = 2048;
    const int qt = blockIdx.x, hh = blockIdx.y, bb = blockIdx.z;
    const int tid = threadIdx.x, lane = tid & 63, wv = tid >> 6;
    const int fr = lane & 15, fq = lane >> 4;
    __shared__ unsigned short kT[64 * 72];
    __shared__ unsigned short vT[64 * 72];
    __shared__ unsigned short pS[4][16 * 72];
    size_t hoff = ((size_t)(bb * 16 + hh)) * S * 64;
    const unsigned short* q = qh + hoff;
    const unsigned short* k = kh + hoff;
    const unsigned short* v = vh + hoff;
    const int srow = tid >> 2, scolv = (tid & 3) * 16;

    // q tile -> LDS (borrow kT), then persistent A-frags
    {
        const unsigned short* src = q + (size_t)(qt * 64 + srow) * 64 + scolv;
        *(s8v*)&kT[srow * 72 + scolv] = *(const s8v*)src;
        *(s8v*)&kT[srow * 72 + scolv + 8] = *(const s8v*)(src + 8);
    }
    __syncthreads();
    s8v aq0 = *(const s8v*)&kT[(wv * 16 + fr) * 72 + fq * 8];
    s8v aq1 = *(const s8v*)&kT[(wv * 16 + fr) * 72 + 32 + fq * 8];
    __syncthreads();

    const int sqbase = qt * 64 + wv * 16 + fq * 4;
    float m0[4], l0[4];
#pragma unroll
    for (int r = 0; r < 4; r++) { m0[r] = -__builtin_huge_valf(); l0[r] = 0.f; }

    // ---- pass 1: row max + sumexp ----
    for (int kt = 0; kt < 32; kt++) {
        int sk0 = kt * 64;
        {
            const unsigned short* src = k + (size_t)(sk0 + srow) * 64 + scolv;
            *(s8v*)&kT[srow * 72 + scolv] = *(const s8v*)src;
            *(s8v*)&kT[srow * 72 + scolv + 8] = *(const s8v*)(src + 8);
        }
        __syncthreads();
        float e[4][4];
#pragma unroll
        for (int t = 0; t < 4; t++) {
            s8v b0 = *(const s8v*)&kT[(t * 16 + fr) * 72 + fq * 8];
            s8v b1 = *(const s8v*)&kT[(t * 16 + fr) * 72 + 32 + fq * 8];
            f4 c = {0.f, 0.f, 0.f, 0.f};
            c = __builtin_amdgcn_mfma_f32_16x16x32_bf16(aq0, b0, c, 0, 0, 0);
            c = __builtin_amdgcn_mfma_f32_16x16x32_bf16(aq1, b1, c, 0, 0, 0);
            int sk = sk0 + t * 16 + fr;
#pragma unroll
            for (int r = 0; r < 4; r++) {
                size_t bidx = ((size_t)bb * S + (sqbase + r)) * S + sk;
                unsigned int wbit = mbits[bidx >> 5];
                e[t][r] = ((wbit >> (bidx & 31)) & 1u) ? c[r] : NEGV;
            }
        }
#pragma unroll
        for (int r = 0; r < 4; r++) {
            float mx = fmaxf(fmaxf(e[0][r], e[1][r]), fmaxf(e[2][r], e[3][r]));
            mx = fmaxf(mx, __shfl_xor(mx, 1));
            mx = fmaxf(mx, __shfl_xor(mx, 2));
            mx = fmaxf(mx, __shfl_xor(mx, 4));
            mx = fmaxf(mx, __shfl_xor(mx, 8));
            float mn = fmaxf(m0[r], mx);
            float sm = __expf(e[0][r] - mn) + __expf(e[1][r] - mn) +
                       __expf(e[2][r] - mn) + __expf(e[3][r] - mn);
            sm += __shfl_xor(sm, 1);
            sm += __shfl_xor(sm, 2);
            sm += __shfl_xor(sm, 4);
            sm += __shfl_xor(sm, 8);
            l0[r] = l0[r] * __expf(m0[r] - mn) + sm;
            m0[r] = mn;
        }
        __syncthreads();
    }
    float li[4];
#pragma unroll
    for (int r = 0; r < 4; r++) li[r] = 1.f / l0[r];

    f4 xacc[4];
#pragma unroll
    for (int ct = 0; ct < 4; ct++) xacc[ct] = (f4){0.f, 0.f, 0.f, 0.f};

    float* attnbase = attn + ((size_t)(bb * 16 + hh)) * S * S;

    // ---- pass 2: recompute, write attention, accumulate PV ----
    for (int kt = 0; kt < 32; kt++) {
        int sk0 = kt * 64;
        {
            const unsigned short* src = k + (size_t)(sk0 + srow) * 64 + scolv;
            *(s8v*)&kT[srow * 72 + scolv] = *(const s8v*)src;
            *(s8v*)&kT[srow * 72 + scolv + 8] = *(const s8v*)(src + 8);
            const unsigned short* vs = v + (size_t)(sk0 + srow) * 64 + scolv;
            s8v v0 = *(const s8v*)vs;
            s8v v1 = *(const s8v*)(vs + 8);
#pragma unroll
            for (int i = 0; i < 8; i++) vT[(scolv + i) * 72 + srow] = (unsigned short)v0[i];
#pragma unroll
            for (int i = 0; i < 8; i++) vT[(scolv + 8 + i) * 72 + srow] = (unsigned short)v1[i];
        }
        __syncthreads();
#pragma unroll
        for (int t = 0; t < 4; t++) {
            s8v b0 = *(const s8v*)&kT[(t * 16 + fr) * 72 + fq * 8];
            s8v b1 = *(const s8v*)&kT[(t * 16 + fr) * 72 + 32 + fq * 8];
            f4 c = {0.f, 0.f, 0.f, 0.f};
            c = __builtin_amdgcn_mfma_f32_16x16x32_bf16(aq0, b0, c, 0, 0, 0);
            c = __builtin_amdgcn_mfma_f32_16x16x32_bf16(aq1, b1, c, 0, 0, 0);
            int sk = sk0 + t * 16 + fr;
#pragma unroll
            for (int r = 0; r < 4; r++) {
                int sq = sqbase + r;
                size_t bidx = ((size_t)bb * S + sq) * S + sk;
                unsigned int wbit = mbits[bidx >> 5];
                float ev = ((wbit >> (bidx & 31)) & 1u) ? c[r] : NEGV;
                float p = __expf(ev - m0[r]) * li[r];
                attnbase[(size_t)sq * S + sk] = p;
                pS[wv][(fq * 4 + r) * 72 + t * 16 + fr] = f2b(p);
            }
        }
        __syncthreads();
#pragma unroll
        for (int s = 0; s < 2; s++) {
            s8v ap = *(const s8v*)&pS[wv][fr * 72 + s * 32 + fq * 8];
#pragma unroll
            for (int ct = 0; ct < 4; ct++) {
                s8v bv = *(const s8v*)&vT[(ct * 16 + fr) * 72 + s * 32 + fq * 8];
                xacc[ct] = __builtin_amdgcn_mfma_f32_16x16x32_bf16(ap, bv, xacc[ct], 0, 0, 0);
            }
        }
        __syncthreads();
    }
#pragma unroll
    for (int ct = 0; ct < 4; ct++) {
#pragma unroll
        for (int r = 0; r < 4; r++) {
            int sq = sqbase + r;
            int d = ct * 16 + fr;
            xh[((size_t)bb * 2048 + sq) * 1024 + hh * 64 + d] = f2b(xacc[ct][r]);
        }
    }
}

extern "C" void kernel_launch(void* const* d_in, const int* in_sizes, int n_in,
                              void* d_out, int out_size, void* d_ws, size_t ws_size,
                              hipStream_t stream) {
    const float* query = (const float*)d_in[0];
    const float* key = (const float*)d_in[1];
    const float* value = (const float*)d_in[2];
    const int* mask = (const int*)d_in[3];
    const float* Wq = (const float*)d_in[4];
    const float* bq = (const float*)d_in[5];
    const float* Wk = (const float*)d_in[6];
    const float* bk = (const float*)d_in[7];
    const float* Wv = (const float*)d_in[8];
    const float* bv = (const float*)d_in[9];
    const float* Wo = (const float*)d_in[10];
    const float* bo = (const float*)d_in[11];

    char* ws = (char*)d_ws;
    const size_t HSZ = 16777216;  // bf16 [4,16,2048,64] bytes
    unsigned short* q_h = (unsigned short*)(ws);
    unsigned short* k_h = (unsigned short*)(ws + HSZ);
    unsigned short* v_h = (unsigned short*)(ws + 2 * HSZ);
    unsigned short* x_h = (unsigned short*)(ws + 3 * HSZ);
    unsigned int* mbits = (unsigned int*)(ws + 4 * HSZ);
    unsigned short* wqb = (unsigned short*)(ws + 4 * HSZ + 2097152);
    unsigned short* wkb = (unsigned short*)(ws + 4 * HSZ + 2 * 2097152);
    unsigned short* wvb = (unsigned short*)(ws + 4 * HSZ + 3 * 2097152);
    unsigned short* wob = (unsigned short*)(ws + 4 * HSZ + 4 * 2097152);

    float* outp = (float*)d_out;
    float* attnp = outp + 8388608;

    pack_mask_kernel<<<2048, 256, 0, stream>>>(mask, mbits);
    cvt_w_kernel<<<dim3(1024, 4), 256, 0, stream>>>(Wq, Wk, Wv, Wo, wqb, wkb, wvb, wob);
    gemm_kernel<false, 0><<<dim3(64, 8), 256, 0, stream>>>(query, wqb, bq, q_h, 0.125f);
    gemm_kernel<false, 0><<<dim3(64, 8), 256, 0, stream>>>(key, wkb, bk, k_h, 1.0f);
    gemm_kernel<false, 0><<<dim3(64, 8), 256, 0, stream>>>(value, wvb, bv, v_h, 1.0f);
    attn_kernel<<<dim3(32, 16, 4), 256, 0, stream>>>(q_h, k_h, v_h, mbits, attnp, x_h);
    gemm_kernel<true, 1><<<dim3(64, 8), 256, 0, stream>>>(x_h, wob, bo, outp, 1.0f);
}